// Round 3
// baseline (559.353 us; speedup 1.0000x reference)
//
#include <hip/hip_runtime.h>
#include <hip/hip_bf16.h>
#include <cstdint>

typedef __bf16 bf16_t;
typedef __attribute__((ext_vector_type(8))) __bf16 bf16x8;
typedef __attribute__((ext_vector_type(4))) __bf16 bf16x4;
typedef __attribute__((ext_vector_type(4))) float f32x4;

#define NEXP 8
#define DK   2048
#define DN   2816
#define DN2  5632
#define NP   8192
#define PPE  1024

// ---------- W1+W3 -> interleaved [E][5632][K]: 16-row groups alternate gate/up ----------
__global__ void k_cvt_w13(const float* __restrict__ W1, const float* __restrict__ W3,
                          bf16_t* __restrict__ dst) {
    const int total4 = NEXP * DN * (DK / 4);
    int stride = gridDim.x * blockDim.x;
    for (int i = blockIdx.x * blockDim.x + threadIdx.x; i < 2 * total4; i += stride) {
        int sel = i >= total4;
        int j   = sel ? i - total4 : i;
        int g   = j >> 9;           // source row (K/4 = 512 vec4 per row)
        int c4  = j & 511;
        int e   = g / DN;
        int n   = g - e * DN;
        long drow = (long)e * DN2 + ((n >> 4) << 5) + (n & 15) + (sel ? 16 : 0);
        float4 v = reinterpret_cast<const float4*>(sel ? W3 : W1)[j];
        bf16x4 o = { (bf16_t)v.x, (bf16_t)v.y, (bf16_t)v.z, (bf16_t)v.w };
        *reinterpret_cast<bf16x4*>(dst + drow * DK + c4 * 4) = o;
    }
}

// ---------- gather x rows by sorted_token_ids, convert to bf16 ----------
__global__ void k_gather(const float* __restrict__ x, const int* __restrict__ ids,
                         bf16_t* __restrict__ xg) {
    int i = blockIdx.x * blockDim.x + threadIdx.x;
    if (i >= NP * (DK / 4)) return;
    int p  = i >> 9;
    int c4 = i & 511;
    int tok = ids[p];
    float4 v = reinterpret_cast<const float4*>(x + (size_t)tok * DK)[c4];
    bf16x4 o = { (bf16_t)v.x, (bf16_t)v.y, (bf16_t)v.z, (bf16_t)v.w };
    *reinterpret_cast<bf16x4*>(xg + (size_t)p * DK + c4 * 4) = o;
}

// ---------- async global->LDS, 16B per lane (wave-uniform LDS base) ----------
__device__ __forceinline__ void gl2lds16(const bf16_t* g, bf16_t* l) {
    __builtin_amdgcn_global_load_lds(
        (__attribute__((address_space(1))) void*)(const_cast<bf16_t*>(g)),
        (__attribute__((address_space(3))) void*)(l), 16, 0, 0);
}

#define BARX()  __builtin_amdgcn_s_barrier()
#define LGKM0() asm volatile("s_waitcnt lgkmcnt(0)" ::: "memory")
#define LGKM8() asm volatile("s_waitcnt lgkmcnt(8)" ::: "memory")
#define VMW6()  asm volatile("s_waitcnt vmcnt(6)" ::: "memory")
#define VMW0()  asm volatile("s_waitcnt vmcnt(0)" ::: "memory")

// stage one 128-row half-tile (2 x global_load_lds per thread, 16B each)
#define STG(ARR, SRC, LD, BUF, HALF, KT) do {                                   \
    gl2lds16((SRC) + (long)((HALF) * 128) * (LD) + (long)(KT) * 64,             \
             &ARR[BUF][(HALF) * 128 + w8][0]);                                  \
    gl2lds16((SRC) + (long)((HALF) * 128 + 64) * (LD) + (long)(KT) * 64,        \
             &ARR[BUF][(HALF) * 128 + 64 + w8][0]);                             \
} while (0)

#define LOADA(DST, BASE) do { _Pragma("unroll")                                 \
    for (int mi_ = 0; mi_ < 4; ++mi_) {                                         \
        DST[mi_][0] = *reinterpret_cast<const bf16x8*>((BASE) + aoff0 + mi_ * 1024); \
        DST[mi_][1] = *reinterpret_cast<const bf16x8*>((BASE) + aoff1 + mi_ * 1024); \
    } } while (0)

#define LOADB(DST, BASE) do { _Pragma("unroll")                                 \
    for (int ni_ = 0; ni_ < 2; ++ni_) {                                         \
        DST[ni_][0] = *reinterpret_cast<const bf16x8*>((BASE) + boff0 + ni_ * 1024); \
        DST[ni_][1] = *reinterpret_cast<const bf16x8*>((BASE) + boff1 + ni_ * 1024); \
    } } while (0)

#define MFMAQ(AF, BF, MIB, NIB) do {                                            \
    __builtin_amdgcn_s_setprio(1);                                              \
    _Pragma("unroll") for (int kk_ = 0; kk_ < 2; ++kk_)                         \
    _Pragma("unroll") for (int mi_ = 0; mi_ < 4; ++mi_)                         \
    _Pragma("unroll") for (int ni_ = 0; ni_ < 2; ++ni_)                         \
        acc[(MIB) + mi_][(NIB) + ni_] = __builtin_amdgcn_mfma_f32_16x16x32_bf16( \
            AF[mi_][kk_], BF[ni_][kk_], acc[(MIB) + mi_][(NIB) + ni_], 0, 0, 0); \
    __builtin_amdgcn_s_setprio(0);                                              \
} while (0)

// ---------- 256x256 8-phase BT GEMM, XOR-swizzled LDS, vmcnt(6) pipeline ----------
// Staging map v2 (region-level WAR ledger verified):
//   prologue: B(t0) A(t0) B(t1) A0(t1);  P1: A1(t+1);  P3: B0+B1(t+2);
//   P4: A0(t+2)+VMW6;  P5: A1(t+2);  P7: B0+B1(t+3);  P8: A0(t+3)+VMW6.
// Every vmcnt(6) leaves exactly {2 B-halves + 1 A-half} in flight; every drained
// load has >=3 phases of flight.
// EPI=0: fused sigmoid(gate)*up epilogue (interleaved B), writes h bf16 [NP][DN];
//        blocks with logical id >= nGemm run the W2 fp32->bf16 convert instead.
// EPI=1: scale by tw[pair], atomicAdd scatter into out fp32 [NTOK][DK].
template <int EPI>
__launch_bounds__(512, 2)
__global__ void k_gemm(const bf16_t* __restrict__ A, const bf16_t* __restrict__ B,
                       bf16_t* __restrict__ Hout, float* __restrict__ Fout,
                       const float* __restrict__ tw, const int* __restrict__ ids,
                       int Mtiles, int Ntiles, int nkt, int lda, int ldb,
                       long aStride, long bStride, int nGemm,
                       const float* __restrict__ cvtSrc, bf16_t* __restrict__ cvtDst,
                       int cvtN4) {
    __shared__ bf16_t As[2][256][64];
    __shared__ bf16_t Bs[2][256][64];

    // XCD-bijective swizzle (grid % 8 == 0): each XCD gets one contiguous chunk
    const int nwg = gridDim.x;
    const int logical = (blockIdx.x & 7) * (nwg >> 3) + (blockIdx.x >> 3);

    if (logical >= nGemm) {
        // ---- W2 convert tail blocks (overlap HBM-bound work with GEMM compute) ----
        int base = (logical - nGemm) * (int)blockDim.x + (int)threadIdx.x;
        int stride = (nwg - nGemm) * (int)blockDim.x;
        for (int i = base; i < cvtN4; i += stride) {
            float4 v = reinterpret_cast<const float4*>(cvtSrc)[i];
            bf16x4 o = { (bf16_t)v.x, (bf16_t)v.y, (bf16_t)v.z, (bf16_t)v.w };
            reinterpret_cast<bf16x4*>(cvtDst)[i] = o;
        }
        return;
    }

    const int tpe = Mtiles * Ntiles;
    const int e  = logical / tpe;
    const int r  = logical - e * tpe;
    const int mt = r / Ntiles;
    const int nt = r - mt * Ntiles;

    const int tid  = threadIdx.x;
    const int w    = tid >> 6;
    const int w8   = w * 8;
    const int lane = tid & 63;
    const int wr = w >> 2, wc = w & 3;        // 2(M) x 4(N) wave grid, 128x64/wave
    const int fr = lane & 15;
    const int fc = lane >> 4;

    // staging source: pre-swizzled global chunk (involution: c' = c ^ (row&7))
    const int srow = tid >> 3;                 // 0..63
    const int schk = (tid & 7) ^ (srow & 7);
    const bf16_t* aSrc = A + (long)e * aStride + ((long)mt * 256 + srow) * lda + schk * 8;
    const bf16_t* bSrc = B + (long)e * bStride + ((long)nt * 256 + srow) * ldb + schk * 8;

    // ds_read element offsets (swizzled): row*64 + (chunk ^ (row&7))*8
    const int sx = lane & 7;
    const int aoff0 = (wr * 128 + fr) * 64 + ((0 + fc) ^ sx) * 8;  // kk=0
    const int aoff1 = (wr * 128 + fr) * 64 + ((4 + fc) ^ sx) * 8;  // kk=1
    const int boff0 = (wc * 64 + fr) * 64 + ((0 + fc) ^ sx) * 8;
    const int boff1 = (wc * 64 + fr) * 64 + ((4 + fc) ^ sx) * 8;

    const bf16_t* As0 = &As[0][0][0];
    const bf16_t* As1 = &As[1][0][0];
    const bf16_t* Bs0 = &Bs[0][0][0];
    const bf16_t* Bs1 = &Bs[1][0][0];

    f32x4 acc[8][4];
#pragma unroll
    for (int a = 0; a < 8; ++a)
#pragma unroll
        for (int b = 0; b < 4; ++b) acc[a][b] = (f32x4){0.f, 0.f, 0.f, 0.f};

    bf16x8 af[4][2], ah[4][2], bl[2][2], bh[2][2];

    // prologue: B(t0), A(t0) -> buf0; B(t1), A0(t1) -> buf1  (14 loads/thread)
    STG(Bs, bSrc, ldb, 0, 0, 0); STG(Bs, bSrc, ldb, 0, 1, 0);
    STG(As, aSrc, lda, 0, 0, 0); STG(As, aSrc, lda, 0, 1, 0);
    STG(Bs, bSrc, ldb, 1, 0, 1); STG(Bs, bSrc, ldb, 1, 1, 1);
    STG(As, aSrc, lda, 1, 0, 1);
    VMW6();           // t0 fully landed; B(t1)+A0(t1) stay in flight
    BARX();

    const int nIter = nkt >> 1;
    for (int it = 0; it < nIter; ++it) {
        const int t = it * 2;
        const bool last = (it == nIter - 1);
        // P1: read af,bl(t) | stage A1(t+1)
        LOADA(af, As0); LOADB(bl, Bs0);
        STG(As, aSrc, lda, 1, 1, t + 1);
        LGKM8();
        BARX(); LGKM0();
        MFMAQ(af, bl, 0, 0);
        BARX();
        // P2: read bh(t)
        LOADB(bh, Bs0 + 2048);
        BARX(); LGKM0();
        MFMAQ(af, bh, 0, 2);
        BARX();
        // P3: read ah(t) | stage B0+B1(t+2)
        LOADA(ah, As0 + 4096);
        if (!last) { STG(Bs, bSrc, ldb, 0, 0, t + 2); STG(Bs, bSrc, ldb, 0, 1, t + 2); }
        BARX(); LGKM0();
        MFMAQ(ah, bh, 4, 2);
        BARX();
        // P4: stage A0(t+2) | vmcnt(6): t+1 fully landed, 3 newest halves in flight
        if (!last) { STG(As, aSrc, lda, 0, 0, t + 2); VMW6(); } else { VMW0(); }
        BARX();
        MFMAQ(ah, bl, 4, 0);
        BARX();
        // P5: read af,bl(t+1) | stage A1(t+2)
        LOADA(af, As1); LOADB(bl, Bs1);
        if (!last) STG(As, aSrc, lda, 0, 1, t + 2);
        LGKM8();
        BARX(); LGKM0();
        MFMAQ(af, bl, 0, 0);
        BARX();
        // P6: read bh(t+1)
        LOADB(bh, Bs1 + 2048);
        BARX(); LGKM0();
        MFMAQ(af, bh, 0, 2);
        BARX();
        // P7: read ah(t+1) | stage B0+B1(t+3)
        LOADA(ah, As1 + 4096);
        if (!last) { STG(Bs, bSrc, ldb, 1, 0, t + 3); STG(Bs, bSrc, ldb, 1, 1, t + 3); }
        BARX(); LGKM0();
        MFMAQ(ah, bh, 4, 2);
        BARX();
        // P8: stage A0(t+3) | vmcnt(6): t+2 fully landed
        if (!last) { STG(As, aSrc, lda, 1, 0, t + 3); VMW6(); } else { VMW0(); }
        BARX();
        MFMAQ(ah, bl, 4, 0);
        BARX();
    }

    if constexpr (EPI == 0) {
        // interleaved cols: ni even = gate, ni odd = up (same real n)
        const long prow0 = (long)e * PPE + (long)mt * 256 + wr * 128 + fc * 4;
        const int col0 = nt * 128 + wc * 32 + fr;
#pragma unroll
        for (int mi = 0; mi < 8; ++mi)
#pragma unroll
            for (int i = 0; i < 4; ++i) {
                long row = prow0 + mi * 16 + i;
#pragma unroll
                for (int p = 0; p < 2; ++p) {
                    float g = acc[mi][2 * p][i];
                    float u = acc[mi][2 * p + 1][i];
                    float s = 1.f / (1.f + __expf(-g));
                    Hout[row * DN + col0 + p * 16] = (bf16_t)(s * u);
                }
            }
    } else {
        const int p0 = e * PPE + mt * 256 + wr * 128 + fc * 4;
        const int col0 = nt * 256 + wc * 64 + fr;
#pragma unroll
        for (int mi = 0; mi < 8; ++mi)
#pragma unroll
            for (int i = 0; i < 4; ++i) {
                int gp = p0 + mi * 16 + i;
                float wgt = tw[gp];
                float* ob = Fout + (long)ids[gp] * DK + col0;
#pragma unroll
                for (int ni = 0; ni < 4; ++ni)
                    atomicAdd(ob + ni * 16, acc[mi][ni][i] * wgt);
            }
    }
}

extern "C" void kernel_launch(void* const* d_in, const int* in_sizes, int n_in,
                              void* d_out, int out_size, void* d_ws, size_t ws_size,
                              hipStream_t stream) {
    const float* x   = (const float*)d_in[0];
    const float* W1  = (const float*)d_in[1];
    const float* W3  = (const float*)d_in[2];
    const float* W2  = (const float*)d_in[3];
    const float* tw  = (const float*)d_in[4];
    const int*   sid = (const int*)d_in[5];
    float* out = (float*)d_out;

    // workspace layout (~357 MB)
    char* ws = (char*)d_ws;
    bf16_t* w13i = (bf16_t*)ws;                      // [E][5632][2048] interleaved, 176MB
    bf16_t* w2b  = (bf16_t*)(ws + 184549376L);       // [E][2048][2816],             88MB
    bf16_t* xg   = (bf16_t*)(ws + 276824064L);       // [8192][2048],                32MB
    bf16_t* h    = (bf16_t*)(ws + 310378496L);       // [8192][2816],                44MB

    hipMemsetAsync(d_out, 0, (size_t)out_size * sizeof(float), stream);

    k_cvt_w13<<<2048, 256, 0, stream>>>(W1, W3, w13i);
    k_gather<<<NP * (DK / 4) / 256, 256, 0, stream>>>(x, sid, xg);

    // GEMM1+act: h[p,n] = sigmoid(xg.W1^T) * (xg.W3^T); +256 tail blocks convert W2
    k_gemm<0><<<NEXP * 4 * 22 + 256, 512, 0, stream>>>(
        xg, w13i, h, nullptr, nullptr, nullptr,
        4, 22, 32, DK, DK, (long)PPE * DK, (long)DN2 * DK,
        NEXP * 4 * 22, W2, w2b, NEXP * DK * (DN / 4));

    // GEMM2: out[tok,k] += tw[p] * h[p,:] . w2b[e,k,:]^T
    k_gemm<1><<<NEXP * 4 * 8, 512, 0, stream>>>(
        h, w2b, nullptr, out, tw, sid,
        4, 8, 44, DN, DN, (long)PPE * DN, (long)DK * DN,
        NEXP * 4 * 8, nullptr, nullptr, 0);
}

// Round 4
// 521.448 us; speedup vs baseline: 1.0727x; 1.0727x over previous
//
#include <hip/hip_runtime.h>
#include <hip/hip_bf16.h>
#include <cstdint>

typedef __bf16 bf16_t;
typedef __attribute__((ext_vector_type(8))) __bf16 bf16x8;
typedef __attribute__((ext_vector_type(4))) __bf16 bf16x4;
typedef __attribute__((ext_vector_type(4))) float f32x4;

#define NEXP 8
#define DK   2048
#define DN   2816
#define DN2  5632
#define NP   8192
#define PPE  1024

// ---------- W1+W3 -> interleaved [E][5632][K]: 16-row groups alternate gate/up ----------
__global__ void k_cvt_w13(const float* __restrict__ W1, const float* __restrict__ W3,
                          bf16_t* __restrict__ dst) {
    const int total4 = NEXP * DN * (DK / 4);
    int stride = gridDim.x * blockDim.x;
    for (int i = blockIdx.x * blockDim.x + threadIdx.x; i < 2 * total4; i += stride) {
        int sel = i >= total4;
        int j   = sel ? i - total4 : i;
        int g   = j >> 9;           // source row (K/4 = 512 vec4 per row)
        int c4  = j & 511;
        int e   = g / DN;
        int n   = g - e * DN;
        long drow = (long)e * DN2 + ((n >> 4) << 5) + (n & 15) + (sel ? 16 : 0);
        float4 v = reinterpret_cast<const float4*>(sel ? W3 : W1)[j];
        bf16x4 o = { (bf16_t)v.x, (bf16_t)v.y, (bf16_t)v.z, (bf16_t)v.w };
        *reinterpret_cast<bf16x4*>(dst + drow * DK + c4 * 4) = o;
    }
}

// ---------- flat fp32 -> bf16 ----------
__global__ void k_cvt(const float* __restrict__ src, bf16_t* __restrict__ dst, int total4) {
    int stride = gridDim.x * blockDim.x;
    for (int i = blockIdx.x * blockDim.x + threadIdx.x; i < total4; i += stride) {
        float4 v = reinterpret_cast<const float4*>(src)[i];
        bf16x4 o = { (bf16_t)v.x, (bf16_t)v.y, (bf16_t)v.z, (bf16_t)v.w };
        reinterpret_cast<bf16x4*>(dst)[i] = o;
    }
}

// ---------- gather x rows by sorted_token_ids, convert to bf16 ----------
__global__ void k_gather(const float* __restrict__ x, const int* __restrict__ ids,
                         bf16_t* __restrict__ xg) {
    int i = blockIdx.x * blockDim.x + threadIdx.x;
    if (i >= NP * (DK / 4)) return;
    int p  = i >> 9;
    int c4 = i & 511;
    int tok = ids[p];
    float4 v = reinterpret_cast<const float4*>(x + (size_t)tok * DK)[c4];
    bf16x4 o = { (bf16_t)v.x, (bf16_t)v.y, (bf16_t)v.z, (bf16_t)v.w };
    *reinterpret_cast<bf16x4*>(xg + (size_t)p * DK + c4 * 4) = o;
}

// ---------- async global->LDS, 16B per lane (wave-uniform LDS base) ----------
__device__ __forceinline__ void gl2lds16(const bf16_t* g, bf16_t* l) {
    __builtin_amdgcn_global_load_lds(
        (__attribute__((address_space(1))) void*)(const_cast<bf16_t*>(g)),
        (__attribute__((address_space(3))) void*)(l), 16, 0, 0);
}

#define BARX()  __builtin_amdgcn_s_barrier()
#define LGKM0() asm volatile("s_waitcnt lgkmcnt(0)" ::: "memory")
#define LGKM8() asm volatile("s_waitcnt lgkmcnt(8)" ::: "memory")
#define VMW6()  asm volatile("s_waitcnt vmcnt(6)" ::: "memory")
#define VMW0()  asm volatile("s_waitcnt vmcnt(0)" ::: "memory")

// stage one 128-row half-tile (2 x global_load_lds per thread, 16B each)
#define STG(ARR, SRC, LD, BUF, HALF, KT) do {                                   \
    gl2lds16((SRC) + (long)((HALF) * 128) * (LD) + (long)(KT) * 64,             \
             &ARR[BUF][(HALF) * 128 + w8][0]);                                  \
    gl2lds16((SRC) + (long)((HALF) * 128 + 64) * (LD) + (long)(KT) * 64,        \
             &ARR[BUF][(HALF) * 128 + 64 + w8][0]);                             \
} while (0)

#define LOADA(DST, BASE) do { _Pragma("unroll")                                 \
    for (int mi_ = 0; mi_ < 4; ++mi_) {                                         \
        DST[mi_][0] = *reinterpret_cast<const bf16x8*>((BASE) + aoff0 + mi_ * 1024); \
        DST[mi_][1] = *reinterpret_cast<const bf16x8*>((BASE) + aoff1 + mi_ * 1024); \
    } } while (0)

#define LOADB(DST, BASE) do { _Pragma("unroll")                                 \
    for (int ni_ = 0; ni_ < 2; ++ni_) {                                         \
        DST[ni_][0] = *reinterpret_cast<const bf16x8*>((BASE) + boff0 + ni_ * 1024); \
        DST[ni_][1] = *reinterpret_cast<const bf16x8*>((BASE) + boff1 + ni_ * 1024); \
    } } while (0)

#define MFMAQ(AF, BF, MIB, NIB) do {                                            \
    __builtin_amdgcn_s_setprio(1);                                              \
    _Pragma("unroll") for (int kk_ = 0; kk_ < 2; ++kk_)                         \
    _Pragma("unroll") for (int mi_ = 0; mi_ < 4; ++mi_)                         \
    _Pragma("unroll") for (int ni_ = 0; ni_ < 2; ++ni_)                         \
        acc[(MIB) + mi_][(NIB) + ni_] = __builtin_amdgcn_mfma_f32_16x16x32_bf16( \
            AF[mi_][kk_], BF[ni_][kk_], acc[(MIB) + mi_][(NIB) + ni_], 0, 0, 0); \
    __builtin_amdgcn_s_setprio(0);                                              \
} while (0)

// ---------- 256x256 8-phase BT GEMM, XOR-swizzled LDS, vmcnt(6) pipeline ----------
// Staging map v2 (region-level WAR ledger verified):
//   prologue: B(t0) A(t0) B(t1) A0(t1);  P1: A1(t+1);  P3: B0+B1(t+2);
//   P4: A0(t+2)+VMW6;  P5: A1(t+2);  P7: B0+B1(t+3);  P8: A0(t+3)+VMW6.
// nt-major block order: the Mtiles blocks sharing a B-panel are consecutive
// logical ids -> co-resident on one XCD -> B served from L2 after first fetch.
// EPI=0: fused sigmoid(gate)*up epilogue (interleaved B), writes h bf16 [NP][DN].
// EPI=1: scale by tw[pair], atomicAdd scatter into out fp32 [NTOK][DK].
template <int EPI>
__launch_bounds__(512, 2)
__global__ void k_gemm(const bf16_t* __restrict__ A, const bf16_t* __restrict__ B,
                       bf16_t* __restrict__ Hout, float* __restrict__ Fout,
                       const float* __restrict__ tw, const int* __restrict__ ids,
                       int Mtiles, int Ntiles, int nkt, int lda, int ldb,
                       long aStride, long bStride) {
    __shared__ bf16_t As[2][256][64];
    __shared__ bf16_t Bs[2][256][64];

    // XCD-bijective swizzle (grid % 8 == 0): each XCD gets one contiguous chunk
    const int nwg = gridDim.x;
    const int logical = (blockIdx.x & 7) * (nwg >> 3) + (blockIdx.x >> 3);
    const int tpe = Mtiles * Ntiles;
    const int e  = logical / tpe;
    const int r  = logical - e * tpe;
    const int nt = r / Mtiles;          // nt-major: B-panel sharers consecutive
    const int mt = r - nt * Mtiles;

    const int tid  = threadIdx.x;
    const int w    = tid >> 6;
    const int w8   = w * 8;
    const int lane = tid & 63;
    const int wr = w >> 2, wc = w & 3;        // 2(M) x 4(N) wave grid, 128x64/wave
    const int fr = lane & 15;
    const int fc = lane >> 4;

    // staging source: pre-swizzled global chunk (involution: c' = c ^ (row&7))
    const int srow = tid >> 3;                 // 0..63
    const int schk = (tid & 7) ^ (srow & 7);
    const bf16_t* aSrc = A + (long)e * aStride + ((long)mt * 256 + srow) * lda + schk * 8;
    const bf16_t* bSrc = B + (long)e * bStride + ((long)nt * 256 + srow) * ldb + schk * 8;

    // ds_read element offsets (swizzled): row*64 + (chunk ^ (row&7))*8
    const int sx = lane & 7;
    const int aoff0 = (wr * 128 + fr) * 64 + ((0 + fc) ^ sx) * 8;  // kk=0
    const int aoff1 = (wr * 128 + fr) * 64 + ((4 + fc) ^ sx) * 8;  // kk=1
    const int boff0 = (wc * 64 + fr) * 64 + ((0 + fc) ^ sx) * 8;
    const int boff1 = (wc * 64 + fr) * 64 + ((4 + fc) ^ sx) * 8;

    const bf16_t* As0 = &As[0][0][0];
    const bf16_t* As1 = &As[1][0][0];
    const bf16_t* Bs0 = &Bs[0][0][0];
    const bf16_t* Bs1 = &Bs[1][0][0];

    f32x4 acc[8][4];
#pragma unroll
    for (int a = 0; a < 8; ++a)
#pragma unroll
        for (int b = 0; b < 4; ++b) acc[a][b] = (f32x4){0.f, 0.f, 0.f, 0.f};

    bf16x8 af[4][2], ah[4][2], bl[2][2], bh[2][2];

    // prologue: B(t0), A(t0) -> buf0; B(t1), A0(t1) -> buf1  (14 loads/thread)
    STG(Bs, bSrc, ldb, 0, 0, 0); STG(Bs, bSrc, ldb, 0, 1, 0);
    STG(As, aSrc, lda, 0, 0, 0); STG(As, aSrc, lda, 0, 1, 0);
    STG(Bs, bSrc, ldb, 1, 0, 1); STG(Bs, bSrc, ldb, 1, 1, 1);
    STG(As, aSrc, lda, 1, 0, 1);
    VMW6();           // t0 fully landed; B(t1)+A0(t1) stay in flight
    BARX();

    const int nIter = nkt >> 1;
    for (int it = 0; it < nIter; ++it) {
        const int t = it * 2;
        const bool last = (it == nIter - 1);
        // P1: read af,bl(t) | stage A1(t+1)
        LOADA(af, As0); LOADB(bl, Bs0);
        STG(As, aSrc, lda, 1, 1, t + 1);
        LGKM8();
        BARX(); LGKM0();
        MFMAQ(af, bl, 0, 0);
        BARX();
        // P2: read bh(t)
        LOADB(bh, Bs0 + 2048);
        BARX(); LGKM0();
        MFMAQ(af, bh, 0, 2);
        BARX();
        // P3: read ah(t) | stage B0+B1(t+2)
        LOADA(ah, As0 + 4096);
        if (!last) { STG(Bs, bSrc, ldb, 0, 0, t + 2); STG(Bs, bSrc, ldb, 0, 1, t + 2); }
        BARX(); LGKM0();
        MFMAQ(ah, bh, 4, 2);
        BARX();
        // P4: stage A0(t+2) | vmcnt(6): t+1 fully landed, 3 newest halves in flight
        if (!last) { STG(As, aSrc, lda, 0, 0, t + 2); VMW6(); } else { VMW0(); }
        BARX();
        MFMAQ(ah, bl, 4, 0);
        BARX();
        // P5: read af,bl(t+1) | stage A1(t+2)
        LOADA(af, As1); LOADB(bl, Bs1);
        if (!last) STG(As, aSrc, lda, 0, 1, t + 2);
        LGKM8();
        BARX(); LGKM0();
        MFMAQ(af, bl, 0, 0);
        BARX();
        // P6: read bh(t+1)
        LOADB(bh, Bs1 + 2048);
        BARX(); LGKM0();
        MFMAQ(af, bh, 0, 2);
        BARX();
        // P7: read ah(t+1) | stage B0+B1(t+3)
        LOADA(ah, As1 + 4096);
        if (!last) { STG(Bs, bSrc, ldb, 1, 0, t + 3); STG(Bs, bSrc, ldb, 1, 1, t + 3); }
        BARX(); LGKM0();
        MFMAQ(ah, bh, 4, 2);
        BARX();
        // P8: stage A0(t+3) | vmcnt(6): t+2 fully landed
        if (!last) { STG(As, aSrc, lda, 1, 0, t + 3); VMW6(); } else { VMW0(); }
        BARX();
        MFMAQ(ah, bl, 4, 0);
        BARX();
    }

    if constexpr (EPI == 0) {
        // interleaved cols: ni even = gate, ni odd = up (same real n)
        const long prow0 = (long)e * PPE + (long)mt * 256 + wr * 128 + fc * 4;
        const int col0 = nt * 128 + wc * 32 + fr;
#pragma unroll
        for (int mi = 0; mi < 8; ++mi)
#pragma unroll
            for (int i = 0; i < 4; ++i) {
                long row = prow0 + mi * 16 + i;
#pragma unroll
                for (int p = 0; p < 2; ++p) {
                    float g = acc[mi][2 * p][i];
                    float u = acc[mi][2 * p + 1][i];
                    float s = 1.f / (1.f + __expf(-g));
                    Hout[row * DN + col0 + p * 16] = (bf16_t)(s * u);
                }
            }
    } else {
        const int p0 = e * PPE + mt * 256 + wr * 128 + fc * 4;
        const int col0 = nt * 256 + wc * 64 + fr;
#pragma unroll
        for (int mi = 0; mi < 8; ++mi)
#pragma unroll
            for (int i = 0; i < 4; ++i) {
                int gp = p0 + mi * 16 + i;
                float wgt = tw[gp];
                float* ob = Fout + (long)ids[gp] * DK + col0;
#pragma unroll
                for (int ni = 0; ni < 4; ++ni)
                    atomicAdd(ob + ni * 16, acc[mi][ni][i] * wgt);
            }
    }
}

extern "C" void kernel_launch(void* const* d_in, const int* in_sizes, int n_in,
                              void* d_out, int out_size, void* d_ws, size_t ws_size,
                              hipStream_t stream) {
    const float* x   = (const float*)d_in[0];
    const float* W1  = (const float*)d_in[1];
    const float* W3  = (const float*)d_in[2];
    const float* W2  = (const float*)d_in[3];
    const float* tw  = (const float*)d_in[4];
    const int*   sid = (const int*)d_in[5];
    float* out = (float*)d_out;

    // workspace layout (~357 MB)
    char* ws = (char*)d_ws;
    bf16_t* w13i = (bf16_t*)ws;                      // [E][5632][2048] interleaved, 176MB
    bf16_t* w2b  = (bf16_t*)(ws + 184549376L);       // [E][2048][2816],             88MB
    bf16_t* xg   = (bf16_t*)(ws + 276824064L);       // [8192][2048],                32MB
    bf16_t* h    = (bf16_t*)(ws + 310378496L);       // [8192][2816],                44MB

    hipMemsetAsync(d_out, 0, (size_t)out_size * sizeof(float), stream);

    k_cvt_w13<<<2048, 256, 0, stream>>>(W1, W3, w13i);
    k_cvt<<<2048, 256, 0, stream>>>(W2, w2b, NEXP * DK * (DN / 4));
    k_gather<<<NP * (DK / 4) / 256, 256, 0, stream>>>(x, sid, xg);

    // GEMM1+act: h[p,n] = sigmoid(xg.W1^T) * (xg.W3^T), interleaved weights
    k_gemm<0><<<NEXP * 4 * 22, 512, 0, stream>>>(
        xg, w13i, h, nullptr, nullptr, nullptr,
        4, 22, 32, DK, DK, (long)PPE * DK, (long)DN2 * DK);

    // GEMM2: out[tok,k] += tw[p] * h[p,:] . w2b[e,k,:]^T
    k_gemm<1><<<NEXP * 4 * 8, 512, 0, stream>>>(
        h, w2b, nullptr, out, tw, sid,
        4, 8, 44, DN, DN, (long)PPE * DN, (long)DK * DN);
}